// Round 3
// baseline (131.698 us; speedup 1.0000x reference)
//
#include <hip/hip_runtime.h>
#include <hip/hip_bf16.h>

#define LPOS 8192
#define HDIM 128
#define M_TOT 4096        // B*Cin
#define N_G   144         // g leading dim (9 MFMA col-tiles)
#define NROW  160         // h2T rows per k8 group: 128 h + ones row + 31 zero (uniform staging)
#define KSPLIT 8
#define KCHUNK (LPOS / KSPLIT)   // 1024
#define NIT    (KCHUNK / 64)     // 16
#define UNITS  (8 * NROW)        // 1280 16-B units per 64-k chunk (5 issues/wave exact)
#define K1_LS 16

typedef float  f32x4 __attribute__((ext_vector_type(4)));
typedef short  s16x8 __attribute__((ext_vector_type(8)));
typedef unsigned int u32x4 __attribute__((ext_vector_type(4)));

__device__ __forceinline__ unsigned short bf16_rne(float f) {
    unsigned u = __builtin_bit_cast(unsigned, f);
    u += 0x7fffu + ((u >> 16) & 1u);
    return (unsigned short)(u >> 16);
}

// ---------------- zero g (avoid rocclr fill path) ----------------
__global__ __launch_bounds__(256) void zero_g(float* __restrict__ g) {
    int i = blockIdx.x * 256 + threadIdx.x;   // grid 576*256 = 147456 = 4096*144/4
    f32x4 z = {0.f, 0.f, 0.f, 0.f};
    ((f32x4*)g)[i] = z;
}

// ---------------- Kernel 1: SIREN -> h2T in LDS-image layout ----------------
// 16-B unit index = chunk*1280 + k8*160 + row; row<128 = h, row 128 = ones, 129..159 = 0
__global__ __launch_bounds__(128) void k1_siren(
        const float* __restrict__ w1, const float* __restrict__ b1,
        const float* __restrict__ w2, const float* __restrict__ b2,
        unsigned short* __restrict__ h2T) {
    __shared__ float w2s[HDIM * 129];
    __shared__ __align__(16) float h1s[HDIM * K1_LS];
    __shared__ unsigned short h2s[HDIM * (K1_LS + 2)];
    const int tid = threadIdx.x;

    for (int idx = tid; idx < HDIM * HDIM; idx += 128)
        w2s[(idx >> 7) * 129 + (idx & 127)] = w2[idx];

    const float myw1 = w1[tid];
    const float myb1 = b1[tid];
    const float myb2 = b2[tid];
    const int l0 = blockIdx.x * K1_LS;

    #pragma unroll
    for (int ls = 0; ls < K1_LS; ls++) {
        float rel = -1.0f + (2.0f / 8191.0f) * (float)(l0 + ls);
        h1s[tid * K1_LS + ls] = sinf(30.0f * (rel * myw1 + myb1));
    }
    __syncthreads();

    float acc[K1_LS];
    #pragma unroll
    for (int ls = 0; ls < K1_LS; ls++) acc[ls] = myb2;

    for (int j = 0; j < HDIM; j++) {
        float wv = w2s[tid * 129 + j];
        const f32x4* hp = (const f32x4*)&h1s[j * K1_LS];
        f32x4 h0 = hp[0], h1 = hp[1], h2 = hp[2], h3 = hp[3];
        acc[0]  += wv * h0[0]; acc[1]  += wv * h0[1]; acc[2]  += wv * h0[2]; acc[3]  += wv * h0[3];
        acc[4]  += wv * h1[0]; acc[5]  += wv * h1[1]; acc[6]  += wv * h1[2]; acc[7]  += wv * h1[3];
        acc[8]  += wv * h2[0]; acc[9]  += wv * h2[1]; acc[10] += wv * h2[2]; acc[11] += wv * h2[3];
        acc[12] += wv * h3[0]; acc[13] += wv * h3[1]; acc[14] += wv * h3[2]; acc[15] += wv * h3[3];
    }

    #pragma unroll
    for (int ls = 0; ls < K1_LS; ls++)
        h2s[tid * (K1_LS + 2) + ls] = bf16_rne(sinf(30.0f * acc[ls]));
    __syncthreads();

    u32x4 o0, o1;
    const int base = tid * (K1_LS + 2);
    #pragma unroll
    for (int q = 0; q < 4; q++) {
        o0[q] = (unsigned)h2s[base + 2 * q]     | ((unsigned)h2s[base + 2 * q + 1] << 16);
        o1[q] = (unsigned)h2s[base + 8 + 2 * q] | ((unsigned)h2s[base + 9 + 2 * q] << 16);
    }
    const size_t c  = (size_t)(l0 >> 6);
    const int    k8 = (l0 >> 3) & 7;   // even; block covers k8, k8+1
    *(u32x4*)(h2T + (c * UNITS + (size_t)k8       * NROW + tid) * 8) = o0;
    *(u32x4*)(h2T + (c * UNITS + (size_t)(k8 + 1) * NROW + tid) * 8) = o1;

    if (tid < 32) {  // rows 128..159: ones row then zeros
        unsigned v = (tid == 0) ? 0x3F803F80u : 0u;
        u32x4 ov = { v, v, v, v };
        *(u32x4*)(h2T + (c * UNITS + (size_t)k8       * NROW + 128 + tid) * 8) = ov;
        *(u32x4*)(h2T + (c * UNITS + (size_t)(k8 + 1) * NROW + 128 + tid) * 8) = ov;
    }
}

// ---------------- Kernel 2: g[m][h] += sum_l x[m][l]*h2e[l][h] (MFMA, T3+T4) --
// 512 blocks (64 M-tiles x 8 K-splits) = 2/CU; 3-buffer LDS pipeline with
// counted vmcnt(5) waits + raw s_barrier (stage for it+1 stays in flight).
__global__ __launch_bounds__(256) void k2_gemm(
        const float* __restrict__ x, const unsigned short* __restrict__ h2T,
        float* __restrict__ g) {
    __shared__ unsigned short lds[3][UNITS * 8];   // 3 x 20480 B

    const int lane = threadIdx.x & 63;
    const int wv   = threadIdx.x >> 6;
    const int r    = lane & 15;
    const int kg   = lane >> 4;
    const int m0   = blockIdx.x * 64 + wv * 16;
    const int kc   = blockIdx.y * KCHUNK;
    const int c0   = kc >> 6;

    const float* xp = x + (size_t)(m0 + r) * LPOS + kc + kg * 8;
    const unsigned short* ssrc = h2T + (size_t)lane * 8;

    auto stage = [&](int ci, int b) {          // exactly 5 issues per wave
        const unsigned short* src = ssrc + (size_t)(c0 + ci) * (UNITS * 8);
        #pragma unroll
        for (int j = 0; j < 5; ++j) {
            const int U = j * 256 + wv * 64;
            __builtin_amdgcn_global_load_lds(
                (const unsigned int*)(src + U * 8),
                (unsigned int*)&lds[b][U * 8], 16, 0, 0);
        }
    };

    f32x4 xr[2][4];
    auto load_x = [&](int sel, int it) {       // exactly 4 issues per wave
        const float* xk = xp + it * 64;
        xr[sel][0] = *(const f32x4*)(xk);
        xr[sel][1] = *(const f32x4*)(xk + 4);
        xr[sel][2] = *(const f32x4*)(xk + 32);
        xr[sel][3] = *(const f32x4*)(xk + 36);
    };

    f32x4 acc[9];
    #pragma unroll
    for (int t = 0; t < 9; t++) { f32x4 z = {0.f, 0.f, 0.f, 0.f}; acc[t] = z; }

    stage(0, 0);        // S0[5]
    load_x(0, 0);       // X0[4]
    stage(1, 1);        // S1[5]   -> outstanding 14

    #pragma unroll
    for (int it = 0; it < NIT; ++it) {
        // steady: keep newest 5 (next stage) in flight; drain S(it) + X(it)
        if (it < NIT - 1) asm volatile("s_waitcnt vmcnt(5)" ::: "memory");
        else              asm volatile("s_waitcnt vmcnt(0)" ::: "memory");
        __builtin_amdgcn_s_barrier();

        if (it + 1 < NIT) load_x((it + 1) & 1, it + 1);
        if (it + 2 < NIT) stage(it + 2, (it + 2) % 3);

        const int sel = it & 1;
        s16x8 aflo, afhi;
        aflo[0] = (short)bf16_rne(xr[sel][0][0]); aflo[1] = (short)bf16_rne(xr[sel][0][1]);
        aflo[2] = (short)bf16_rne(xr[sel][0][2]); aflo[3] = (short)bf16_rne(xr[sel][0][3]);
        aflo[4] = (short)bf16_rne(xr[sel][1][0]); aflo[5] = (short)bf16_rne(xr[sel][1][1]);
        aflo[6] = (short)bf16_rne(xr[sel][1][2]); aflo[7] = (short)bf16_rne(xr[sel][1][3]);
        afhi[0] = (short)bf16_rne(xr[sel][2][0]); afhi[1] = (short)bf16_rne(xr[sel][2][1]);
        afhi[2] = (short)bf16_rne(xr[sel][2][2]); afhi[3] = (short)bf16_rne(xr[sel][2][3]);
        afhi[4] = (short)bf16_rne(xr[sel][3][0]); afhi[5] = (short)bf16_rne(xr[sel][3][1]);
        afhi[6] = (short)bf16_rne(xr[sel][3][2]); afhi[7] = (short)bf16_rne(xr[sel][3][3]);

        const unsigned short* buf = &lds[it % 3][0];
        #pragma unroll
        for (int t = 0; t < 9; t++) {
            s16x8 blo = *(const s16x8*)(buf + ((kg    ) * NROW + t * 16 + r) * 8);
            s16x8 bhi = *(const s16x8*)(buf + ((kg + 4) * NROW + t * 16 + r) * 8);
            acc[t] = __builtin_amdgcn_mfma_f32_16x16x32_bf16(aflo, blo, acc[t], 0, 0, 0);
            acc[t] = __builtin_amdgcn_mfma_f32_16x16x32_bf16(afhi, bhi, acc[t], 0, 0, 0);
        }
    }

    // C/D layout: col = lane&15, row = (lane>>4)*4 + q
    #pragma unroll
    for (int t = 0; t < 9; t++) {
        const int col = t * 16 + r;
        #pragma unroll
        for (int q = 0; q < 4; q++) {
            const int row = m0 + kg * 4 + q;
            unsafeAtomicAdd(&g[(size_t)row * N_G + col], acc[t][q]);
        }
    }
}

// ---------------- Kernel 3: out[b,o] = sum_{i,h} g[b,i,h]*w3e[o*64+i,h] ------
// 64 blocks (one per b); g[b] staged in LDS; thread = (o = t>>2, q = t&3):
// q covers h in [q*32, q*32+32), q==0 also h=128 (b3 term); shfl-reduce over q.
__global__ __launch_bounds__(256) void k3_contract(
        const float* __restrict__ g, const float* __restrict__ w3,
        const float* __restrict__ b3, const float* __restrict__ bias,
        float* __restrict__ out) {
    __shared__ __align__(16) float gs[64][132];
    const int b = blockIdx.x;
    const int t = threadIdx.x;

    for (int idx = t; idx < 64 * 129; idx += 256) {
        int i = idx / 129;
        int h = idx - i * 129;
        gs[i][h] = g[(size_t)(b * 64 + i) * N_G + h];
    }
    __syncthreads();

    const int o = t >> 2;
    const int q = t & 3;
    const int hbase = q * 32;
    float acc = 0.0f;
    const float* w3o = w3 + (size_t)(o * 64) * HDIM;
    const float* b3o = b3 + o * 64;

    for (int i = 0; i < 64; ++i) {
        const float* wr = w3o + i * HDIM + hbase;
        const float* gp = &gs[i][hbase];
        #pragma unroll
        for (int j = 0; j < 8; ++j) {
            f32x4 w4 = *(const f32x4*)(wr + j * 4);
            f32x4 g4 = *(const f32x4*)(gp + j * 4);
            acc += w4[0] * g4[0] + w4[1] * g4[1] + w4[2] * g4[2] + w4[3] * g4[3];
        }
        if (q == 0) acc += gs[i][128] * b3o[i];
    }
    acc += __shfl_xor(acc, 1);
    acc += __shfl_xor(acc, 2);
    if (q == 0) out[b * 64 + o] = acc + bias[o];
}

extern "C" void kernel_launch(void* const* d_in, const int* in_sizes, int n_in,
                              void* d_out, int out_size, void* d_ws, size_t ws_size,
                              hipStream_t stream) {
    const float* x    = (const float*)d_in[0];
    const float* w1   = (const float*)d_in[1];
    const float* b1   = (const float*)d_in[2];
    const float* w2   = (const float*)d_in[3];
    const float* b2   = (const float*)d_in[4];
    const float* w3   = (const float*)d_in[5];
    const float* b3   = (const float*)d_in[6];
    const float* bias = (const float*)d_in[7];
    float* out = (float*)d_out;

    unsigned short* h2T = (unsigned short*)d_ws;
    const size_t H2T_BYTES = (size_t)(LPOS / 64) * UNITS * 16;   // 2.62 MB
    float* g = (float*)((char*)d_ws + H2T_BYTES);                // 2.36 MB

    zero_g<<<576, 256, 0, stream>>>(g);
    k1_siren<<<LPOS / K1_LS, 128, 0, stream>>>(w1, b1, w2, b2, h2T);
    k2_gemm<<<dim3(M_TOT / 64, KSPLIT), 256, 0, stream>>>(x, h2T, g);
    k3_contract<<<64, 256, 0, stream>>>(g, w3, b3, bias, out);
}

// Round 4
// 88.862 us; speedup vs baseline: 1.4820x; 1.4820x over previous
//
#include <hip/hip_runtime.h>
#include <hip/hip_bf16.h>

#define LPOS 8192
#define HDIM 128
#define M_TOT 4096        // B*Cin
#define N_G   144         // g leading dim (9 MFMA col-tiles)
#define NROW  160         // h2T rows per k8 group: 128 h + ones row + 31 zero (uniform staging)
#define KSPLIT 16
#define KCHUNK (LPOS / KSPLIT)   // 512
#define NIT    (KCHUNK / 64)     // 8
#define UNITS  (8 * NROW)        // 1280 16-B units per 64-k chunk (5 issues/wave exact)
#define K1_LS 16

typedef float  f32x4 __attribute__((ext_vector_type(4)));
typedef short  s16x8 __attribute__((ext_vector_type(8)));
typedef unsigned int u32x4 __attribute__((ext_vector_type(4)));

__device__ __forceinline__ unsigned short bf16_rne(float f) {
    unsigned u = __builtin_bit_cast(unsigned, f);
    u += 0x7fffu + ((u >> 16) & 1u);
    return (unsigned short)(u >> 16);
}

// ---------------- Kernel 1: SIREN -> h2T in LDS-image layout ----------------
// 16-B unit index = chunk*1280 + k8*160 + row; row<128 = h, row 128 = ones, 129..159 = 0
__global__ __launch_bounds__(128) void k1_siren(
        const float* __restrict__ w1, const float* __restrict__ b1,
        const float* __restrict__ w2, const float* __restrict__ b2,
        unsigned short* __restrict__ h2T) {
    __shared__ float w2s[HDIM * 129];
    __shared__ __align__(16) float h1s[HDIM * K1_LS];
    __shared__ unsigned short h2s[HDIM * (K1_LS + 2)];
    const int tid = threadIdx.x;

    for (int idx = tid; idx < HDIM * HDIM; idx += 128)
        w2s[(idx >> 7) * 129 + (idx & 127)] = w2[idx];

    const float myw1 = w1[tid];
    const float myb1 = b1[tid];
    const float myb2 = b2[tid];
    const int l0 = blockIdx.x * K1_LS;

    #pragma unroll
    for (int ls = 0; ls < K1_LS; ls++) {
        float rel = -1.0f + (2.0f / 8191.0f) * (float)(l0 + ls);
        h1s[tid * K1_LS + ls] = sinf(30.0f * (rel * myw1 + myb1));
    }
    __syncthreads();

    float acc[K1_LS];
    #pragma unroll
    for (int ls = 0; ls < K1_LS; ls++) acc[ls] = myb2;

    for (int j = 0; j < HDIM; j++) {
        float wv = w2s[tid * 129 + j];
        const f32x4* hp = (const f32x4*)&h1s[j * K1_LS];
        f32x4 h0 = hp[0], h1 = hp[1], h2 = hp[2], h3 = hp[3];
        acc[0]  += wv * h0[0]; acc[1]  += wv * h0[1]; acc[2]  += wv * h0[2]; acc[3]  += wv * h0[3];
        acc[4]  += wv * h1[0]; acc[5]  += wv * h1[1]; acc[6]  += wv * h1[2]; acc[7]  += wv * h1[3];
        acc[8]  += wv * h2[0]; acc[9]  += wv * h2[1]; acc[10] += wv * h2[2]; acc[11] += wv * h2[3];
        acc[12] += wv * h3[0]; acc[13] += wv * h3[1]; acc[14] += wv * h3[2]; acc[15] += wv * h3[3];
    }

    #pragma unroll
    for (int ls = 0; ls < K1_LS; ls++)
        h2s[tid * (K1_LS + 2) + ls] = bf16_rne(sinf(30.0f * acc[ls]));
    __syncthreads();

    u32x4 o0, o1;
    const int base = tid * (K1_LS + 2);
    #pragma unroll
    for (int q = 0; q < 4; q++) {
        o0[q] = (unsigned)h2s[base + 2 * q]     | ((unsigned)h2s[base + 2 * q + 1] << 16);
        o1[q] = (unsigned)h2s[base + 8 + 2 * q] | ((unsigned)h2s[base + 9 + 2 * q] << 16);
    }
    const size_t c  = (size_t)(l0 >> 6);
    const int    k8 = (l0 >> 3) & 7;   // even; block covers k8, k8+1
    *(u32x4*)(h2T + (c * UNITS + (size_t)k8       * NROW + tid) * 8) = o0;
    *(u32x4*)(h2T + (c * UNITS + (size_t)(k8 + 1) * NROW + tid) * 8) = o1;

    if (tid < 32) {  // rows 128..159: ones row then zeros
        unsigned v = (tid == 0) ? 0x3F803F80u : 0u;
        u32x4 ov = { v, v, v, v };
        *(u32x4*)(h2T + (c * UNITS + (size_t)k8       * NROW + 128 + tid) * 8) = ov;
        *(u32x4*)(h2T + (c * UNITS + (size_t)(k8 + 1) * NROW + 128 + tid) * 8) = ov;
    }
}

// ---------------- Kernel 2: g_part[y][m][h] = sum_{l in chunk y} x[m][l]*h2e[l][h]
// R2-proven loop shape (2-buf LDS, 4 blocks/CU, __syncthreads pipeline);
// epilogue = plain coalesced stores (NO atomics — they were the 30-50 us cost).
__global__ __launch_bounds__(256) void k2_gemm(
        const float* __restrict__ x, const unsigned short* __restrict__ h2T,
        float* __restrict__ gp) {
    __shared__ unsigned short lds[2][UNITS * 8];   // 2 x 20480 B

    const int lane = threadIdx.x & 63;
    const int wv   = threadIdx.x >> 6;
    const int r    = lane & 15;
    const int kg   = lane >> 4;
    const int m0   = blockIdx.x * 64 + wv * 16;
    const int y    = blockIdx.y;
    const int kc   = y * KCHUNK;
    const int c0   = kc >> 6;

    const float* xp = x + (size_t)(m0 + r) * LPOS + kc + kg * 8;
    const unsigned short* ssrc = h2T + (size_t)lane * 8;

    auto stage = [&](int ci, int b) {          // exactly 5 issues per wave
        const unsigned short* src = ssrc + (size_t)(c0 + ci) * (UNITS * 8);
        #pragma unroll
        for (int j = 0; j < 5; ++j) {
            const int U = j * 256 + wv * 64;
            __builtin_amdgcn_global_load_lds(
                (const unsigned int*)(src + (size_t)U * 8),
                (unsigned int*)&lds[b][U * 8], 16, 0, 0);
        }
    };

    f32x4 acc[9];
    #pragma unroll
    for (int t = 0; t < 9; t++) { f32x4 z = {0.f, 0.f, 0.f, 0.f}; acc[t] = z; }

    stage(0, 0);
    __syncthreads();

    for (int it = 0; it < NIT; ++it) {
        const float* xk = xp + it * 64;
        f32x4 a0 = *(const f32x4*)(xk);
        f32x4 a1 = *(const f32x4*)(xk + 4);
        f32x4 a2 = *(const f32x4*)(xk + 32);
        f32x4 a3 = *(const f32x4*)(xk + 36);

        if (it + 1 < NIT) stage(it + 1, (it + 1) & 1);

        s16x8 aflo, afhi;
        aflo[0] = (short)bf16_rne(a0[0]); aflo[1] = (short)bf16_rne(a0[1]);
        aflo[2] = (short)bf16_rne(a0[2]); aflo[3] = (short)bf16_rne(a0[3]);
        aflo[4] = (short)bf16_rne(a1[0]); aflo[5] = (short)bf16_rne(a1[1]);
        aflo[6] = (short)bf16_rne(a1[2]); aflo[7] = (short)bf16_rne(a1[3]);
        afhi[0] = (short)bf16_rne(a2[0]); afhi[1] = (short)bf16_rne(a2[1]);
        afhi[2] = (short)bf16_rne(a2[2]); afhi[3] = (short)bf16_rne(a2[3]);
        afhi[4] = (short)bf16_rne(a3[0]); afhi[5] = (short)bf16_rne(a3[1]);
        afhi[6] = (short)bf16_rne(a3[2]); afhi[7] = (short)bf16_rne(a3[3]);

        const unsigned short* buf = &lds[it & 1][0];
        #pragma unroll
        for (int t = 0; t < 9; t++) {
            s16x8 blo = *(const s16x8*)(buf + ((kg    ) * NROW + t * 16 + r) * 8);
            s16x8 bhi = *(const s16x8*)(buf + ((kg + 4) * NROW + t * 16 + r) * 8);
            acc[t] = __builtin_amdgcn_mfma_f32_16x16x32_bf16(aflo, blo, acc[t], 0, 0, 0);
            acc[t] = __builtin_amdgcn_mfma_f32_16x16x32_bf16(afhi, bhi, acc[t], 0, 0, 0);
        }
        __syncthreads();
    }

    // C/D layout: col = lane&15, row = (lane>>4)*4 + q. Plain stores to g_part[y].
    float* gpy = gp + (size_t)y * M_TOT * N_G;
    #pragma unroll
    for (int t = 0; t < 9; t++) {
        const int col = t * 16 + r;
        #pragma unroll
        for (int q = 0; q < 4; q++) {
            const int row = m0 + kg * 4 + q;
            gpy[(size_t)row * N_G + col] = acc[t][q];
        }
    }
}

// ---------------- reduce: g[m][h] = sum_y g_part[y][m][h] ----------------
__global__ __launch_bounds__(256) void reduce_g(
        const float* __restrict__ gp, float* __restrict__ g) {
    const int i = blockIdx.x * 256 + threadIdx.x;   // grid 576 -> 147456 f32x4
    f32x4 s = {0.f, 0.f, 0.f, 0.f};
    #pragma unroll
    for (int y = 0; y < KSPLIT; ++y) {
        f32x4 v = ((const f32x4*)(gp + (size_t)y * M_TOT * N_G))[i];
        s[0] += v[0]; s[1] += v[1]; s[2] += v[2]; s[3] += v[3];
    }
    ((f32x4*)g)[i] = s;
}

// ---------------- Kernel 3: out[b,o] = sum_{i,h<=128} g[b,i,h]*w3e[o*64+i,h] --
// R2-proven 4096-block version (per (b,o); g slice L2-hot across the 64 o-blocks).
__global__ __launch_bounds__(256) void k3_contract(
        const float* __restrict__ g, const float* __restrict__ w3,
        const float* __restrict__ b3, const float* __restrict__ bias,
        float* __restrict__ out) {
    const int b = blockIdx.x >> 6;
    const int o = blockIdx.x & 63;
    __shared__ float red[256];
    float acc = 0.0f;
    for (int idx = threadIdx.x; idx < 64 * 129; idx += 256) {
        int i = idx / 129;
        int h = idx - i * 129;
        float gv = g[(size_t)(b * 64 + i) * N_G + h];
        float wvv = (h < HDIM) ? w3[(size_t)(o * 64 + i) * HDIM + h] : b3[o * 64 + i];
        acc += gv * wvv;
    }
    red[threadIdx.x] = acc;
    __syncthreads();
    for (int s = 128; s > 0; s >>= 1) {
        if (threadIdx.x < s) red[threadIdx.x] += red[threadIdx.x + s];
        __syncthreads();
    }
    if (threadIdx.x == 0) out[blockIdx.x] = red[0] + bias[o];
}

extern "C" void kernel_launch(void* const* d_in, const int* in_sizes, int n_in,
                              void* d_out, int out_size, void* d_ws, size_t ws_size,
                              hipStream_t stream) {
    const float* x    = (const float*)d_in[0];
    const float* w1   = (const float*)d_in[1];
    const float* b1   = (const float*)d_in[2];
    const float* w2   = (const float*)d_in[3];
    const float* b2   = (const float*)d_in[4];
    const float* w3   = (const float*)d_in[5];
    const float* b3   = (const float*)d_in[6];
    const float* bias = (const float*)d_in[7];
    float* out = (float*)d_out;

    unsigned short* h2T = (unsigned short*)d_ws;
    const size_t H2T_BYTES = (size_t)(LPOS / 64) * UNITS * 16;       // 2.62 MB
    float* gp = (float*)((char*)d_ws + H2T_BYTES);                   // 16 x 2.36 MB
    const size_t GP_BYTES = (size_t)KSPLIT * M_TOT * N_G * 4;        // 37.7 MB
    float* g = (float*)((char*)d_ws + H2T_BYTES + GP_BYTES);         // 2.36 MB

    k1_siren<<<LPOS / K1_LS, 128, 0, stream>>>(w1, b1, w2, b2, h2T);
    k2_gemm<<<dim3(M_TOT / 64, KSPLIT), 256, 0, stream>>>(x, h2T, gp);
    reduce_g<<<M_TOT * N_G / 4 / 256, 256, 0, stream>>>(gp, g);
    k3_contract<<<64 * 64, 256, 0, stream>>>(g, w3, b3, bias, out);
}

// Round 5
// 85.925 us; speedup vs baseline: 1.5327x; 1.0342x over previous
//
#include <hip/hip_runtime.h>
#include <hip/hip_bf16.h>

#define LPOS 8192
#define HDIM 128
#define M_TOT 4096          // B*Cin
#define GROW  132           // g/gp row stride (129 used: 128 h + col128 = sum(x); 3 pad)
#define GELEMS (M_TOT * GROW)        // 540672
#define KSPLIT 32
#define KCHUNK (LPOS / KSPLIT)       // 256 k per block = 4 chunks of 64
#define CUNITS 1024                  // 16-B units per 64-k chunk (8 k8 x 128 rows)
#define BUNITS (4 * CUNITS)          // 4096 units = 65536 B LDS

typedef float  f32x4 __attribute__((ext_vector_type(4)));
typedef short  s16x8 __attribute__((ext_vector_type(8)));
typedef unsigned int u32x2 __attribute__((ext_vector_type(2)));
typedef unsigned int u32x4 __attribute__((ext_vector_type(4)));

__device__ __forceinline__ unsigned short bf16_rne(float f) {
    unsigned u = __builtin_bit_cast(unsigned, f);
    u += 0x7fffu + ((u >> 16) & 1u);
    return (unsigned short)(u >> 16);
}

__device__ __forceinline__ s16x8 cvt8(f32x4 a, f32x4 b) {
    s16x8 r;
    r[0] = (short)bf16_rne(a[0]); r[1] = (short)bf16_rne(a[1]);
    r[2] = (short)bf16_rne(a[2]); r[3] = (short)bf16_rne(a[3]);
    r[4] = (short)bf16_rne(b[0]); r[5] = (short)bf16_rne(b[1]);
    r[6] = (short)bf16_rne(b[2]); r[7] = (short)bf16_rne(b[3]);
    return r;
}

__device__ __forceinline__ float sum8(f32x4 a, f32x4 b) {
    return ((a[0] + a[1]) + (a[2] + a[3])) + ((b[0] + b[1]) + (b[2] + b[3]));
}

// ---------------- Kernel 1: SIREN -> h2T -------------------------------------
// h2T 16-B units: unit = chunk*1024 + k8*128 + h   (chunk = l/64, k8 = (l/8)%8)
// Each unit = 8 consecutive l's (bf16) for one h. No pad rows (col128 via VALU in k2).
__global__ __launch_bounds__(256) void k1_siren(
        const float* __restrict__ w1, const float* __restrict__ b1,
        const float* __restrict__ w2, const float* __restrict__ b2,
        unsigned short* __restrict__ h2T) {
    __shared__ float w2sT[HDIM * 129];              // [j][h] transposed, +1 pad
    __shared__ __align__(16) float h1s[2][HDIM * 8];
    const int tid = threadIdx.x;
    const int s = tid >> 7;          // sub-tile (two 8-l tiles per block)
    const int h = tid & 127;

    // coalesced global read, conflict-free transposed LDS write (129 = 1 mod 32)
    for (int idx = tid; idx < HDIM * HDIM; idx += 256)
        w2sT[(idx & 127) * 129 + (idx >> 7)] = w2[idx];

    const int l0 = blockIdx.x * 16 + s * 8;
    const float myw1 = w1[h], myb1 = b1[h];
    #pragma unroll
    for (int ls = 0; ls < 8; ++ls) {
        float rel = -1.0f + (2.0f / 8191.0f) * (float)(l0 + ls);
        h1s[s][h * 8 + ls] = __sinf(30.0f * (rel * myw1 + myb1));
    }
    __syncthreads();

    const float bb = b2[h];
    float acc[8];
    #pragma unroll
    for (int ls = 0; ls < 8; ++ls) acc[ls] = bb;

    for (int j = 0; j < HDIM; ++j) {
        float wv = w2sT[j * 129 + h];
        const f32x4* hp = (const f32x4*)&h1s[s][j * 8];
        f32x4 p0 = hp[0], p1 = hp[1];
        acc[0] += wv * p0[0]; acc[1] += wv * p0[1];
        acc[2] += wv * p0[2]; acc[3] += wv * p0[3];
        acc[4] += wv * p1[0]; acc[5] += wv * p1[1];
        acc[6] += wv * p1[2]; acc[7] += wv * p1[3];
    }

    u32x4 ov;
    #pragma unroll
    for (int q = 0; q < 4; ++q) {
        unsigned lo = bf16_rne(__sinf(30.0f * acc[2 * q]));
        unsigned hi = bf16_rne(__sinf(30.0f * acc[2 * q + 1]));
        ov[q] = lo | (hi << 16);
    }
    const size_t c = (size_t)(l0 >> 6);
    const int k8 = (l0 >> 3) & 7;
    *(u32x4*)(h2T + (c * CUNITS + (size_t)k8 * 128 + h) * 8) = ov;
}

// ---------------- Kernel 2: gp[y][m][*] partial GEMM (barrier-free inner loop)
// Block = 128 M-rows x 256 k. B (64 KB) staged ONCE -> one barrier -> 4 unrolled
// iters of {cvt, 16 ds_read_b128, 32 MFMA}, x prefetched 2 iters deep.
// col 0..127 = MFMA; col 128 = f32 row-sum of x (carries b3 term).
__global__ __launch_bounds__(256, 2) void k2_gemm(
        const float* __restrict__ x, const unsigned short* __restrict__ h2T,
        unsigned short* __restrict__ gp) {
    __shared__ unsigned short lds[BUNITS * 8];     // 65536 B

    const int lane = threadIdx.x & 63;
    const int wv   = threadIdx.x >> 6;
    const int r    = lane & 15;
    const int kg   = lane >> 4;
    const int m0   = blockIdx.x * 128;
    const int y    = blockIdx.y;
    const int kc   = y * KCHUNK;

    // stage whole B chunk-group: contiguous 64 KB, 16 issues/thread
    {
        const unsigned short* src = h2T + (size_t)y * (BUNITS * 8);
        #pragma unroll
        for (int j = 0; j < 16; ++j) {
            const int U = j * 256 + threadIdx.x;
            __builtin_amdgcn_global_load_lds(
                (const unsigned int*)(src + (size_t)U * 8),
                (unsigned int*)&lds[U * 8], 16, 0, 0);
        }
    }

    const float* xpa = x + (size_t)(m0 + wv * 32 + r) * LPOS + kc + kg * 8;
    const float* xpb = xpa + 16 * LPOS;

    f32x4 xr[2][2][4];
#define LOADX(SL, IT) do { \
        xr[SL][0][0] = *(const f32x4*)(xpa + (IT) * 64);      \
        xr[SL][0][1] = *(const f32x4*)(xpa + (IT) * 64 + 4);  \
        xr[SL][0][2] = *(const f32x4*)(xpa + (IT) * 64 + 32); \
        xr[SL][0][3] = *(const f32x4*)(xpa + (IT) * 64 + 36); \
        xr[SL][1][0] = *(const f32x4*)(xpb + (IT) * 64);      \
        xr[SL][1][1] = *(const f32x4*)(xpb + (IT) * 64 + 4);  \
        xr[SL][1][2] = *(const f32x4*)(xpb + (IT) * 64 + 32); \
        xr[SL][1][3] = *(const f32x4*)(xpb + (IT) * 64 + 36); \
    } while (0)

    LOADX(0, 0);
    LOADX(1, 1);

    f32x4 acc[2][8];
    #pragma unroll
    for (int s = 0; s < 2; ++s)
        #pragma unroll
        for (int t = 0; t < 8; ++t) { f32x4 z = {0.f, 0.f, 0.f, 0.f}; acc[s][t] = z; }
    float sacc0 = 0.f, sacc1 = 0.f;

    __syncthreads();   // B staged; only barrier in the kernel

    #pragma unroll
    for (int it = 0; it < 4; ++it) {
        const int sl = it & 1;
        s16x8 a0lo = cvt8(xr[sl][0][0], xr[sl][0][1]);
        s16x8 a0hi = cvt8(xr[sl][0][2], xr[sl][0][3]);
        s16x8 a1lo = cvt8(xr[sl][1][0], xr[sl][1][1]);
        s16x8 a1hi = cvt8(xr[sl][1][2], xr[sl][1][3]);
        sacc0 += sum8(xr[sl][0][0], xr[sl][0][1]) + sum8(xr[sl][0][2], xr[sl][0][3]);
        sacc1 += sum8(xr[sl][1][0], xr[sl][1][1]) + sum8(xr[sl][1][2], xr[sl][1][3]);

        if (it + 2 < 4) LOADX(sl, it + 2);   // prefetch 2 deep (WAR keeps order)

        #pragma unroll
        for (int t = 0; t < 8; ++t) {
            s16x8 blo = *(const s16x8*)&lds[((size_t)it * CUNITS + kg * 128 + t * 16 + r) * 8];
            s16x8 bhi = *(const s16x8*)&lds[((size_t)it * CUNITS + (kg + 4) * 128 + t * 16 + r) * 8];
            acc[0][t] = __builtin_amdgcn_mfma_f32_16x16x32_bf16(a0lo, blo, acc[0][t], 0, 0, 0);
            acc[0][t] = __builtin_amdgcn_mfma_f32_16x16x32_bf16(a0hi, bhi, acc[0][t], 0, 0, 0);
            acc[1][t] = __builtin_amdgcn_mfma_f32_16x16x32_bf16(a1lo, blo, acc[1][t], 0, 0, 0);
            acc[1][t] = __builtin_amdgcn_mfma_f32_16x16x32_bf16(a1hi, bhi, acc[1][t], 0, 0, 0);
        }
    }
#undef LOADX

    // C/D layout: col = t*16 + r, row = base + kg*4 + q
    unsigned short* gpy = gp + (size_t)y * GELEMS;
    #pragma unroll
    for (int s = 0; s < 2; ++s) {
        #pragma unroll
        for (int t = 0; t < 8; ++t) {
            const int col = t * 16 + r;
            #pragma unroll
            for (int q = 0; q < 4; ++q) {
                const int row = m0 + wv * 32 + s * 16 + kg * 4 + q;
                gpy[(size_t)row * GROW + col] = bf16_rne(acc[s][t][q]);
            }
        }
    }
    // col 128: reduce the 4 kg-slices of each row across lanes (bits 4,5)
    sacc0 += __shfl_xor(sacc0, 16); sacc0 += __shfl_xor(sacc0, 32);
    sacc1 += __shfl_xor(sacc1, 16); sacc1 += __shfl_xor(sacc1, 32);
    if (kg == 0) {
        gpy[(size_t)(m0 + wv * 32 + r) * GROW + 128]      = bf16_rne(sacc0);
        gpy[(size_t)(m0 + wv * 32 + 16 + r) * GROW + 128] = bf16_rne(sacc1);
    }
}

// ---------------- reduce: g[f] = sum_y gp[y][f]  (bf16 -> f32) ---------------
__global__ __launch_bounds__(256) void reduce_g(
        const unsigned short* __restrict__ gp, float* __restrict__ g) {
    const int t = blockIdx.x * 256 + threadIdx.x;   // 135168 threads x 4 elems
    const unsigned int* p = (const unsigned int*)gp;
    float s0 = 0.f, s1 = 0.f, s2 = 0.f, s3 = 0.f;
    #pragma unroll 8
    for (int y = 0; y < KSPLIT; ++y) {
        u32x2 v = *(const u32x2*)(p + (size_t)y * (GELEMS / 2) + (size_t)t * 2);
        s0 += __builtin_bit_cast(float, v[0] << 16);
        s1 += __builtin_bit_cast(float, v[0] & 0xffff0000u);
        s2 += __builtin_bit_cast(float, v[1] << 16);
        s3 += __builtin_bit_cast(float, v[1] & 0xffff0000u);
    }
    f32x4 o = {s0, s1, s2, s3};
    *(f32x4*)(g + (size_t)t * 4) = o;
}

// ---------------- Kernel 3: out[b,o] = sum_{i,h} g[b,i,h]*w3e[o*64+i,h] ------
// Block per (b,o); thread (i = t>>2, q = t&3) covers h in [q*32, q*32+32) with
// f32x4 loads; q==0 adds the b3 term (col 128); shfl over q, LDS+shfl over i.
__global__ __launch_bounds__(256) void k3_contract(
        const float* __restrict__ g, const float* __restrict__ w3,
        const float* __restrict__ b3, const float* __restrict__ bias,
        float* __restrict__ out) {
    const int b = blockIdx.x >> 6;
    const int o = blockIdx.x & 63;
    const int t = threadIdx.x;
    const int i = t >> 2;
    const int q = t & 3;
    __shared__ float red[64];

    const float* gi = g + (size_t)(b * 64 + i) * GROW + q * 32;
    const float* wi = w3 + (size_t)(o * 64 + i) * HDIM + q * 32;
    float acc = 0.f;
    #pragma unroll
    for (int j = 0; j < 8; ++j) {
        f32x4 gv = *(const f32x4*)(gi + j * 4);
        f32x4 wv = *(const f32x4*)(wi + j * 4);
        acc += gv[0] * wv[0] + gv[1] * wv[1] + gv[2] * wv[2] + gv[3] * wv[3];
    }
    if (q == 0) acc += g[(size_t)(b * 64 + i) * GROW + 128] * b3[o * 64 + i];
    acc += __shfl_xor(acc, 1);
    acc += __shfl_xor(acc, 2);
    if (q == 0) red[i] = acc;
    __syncthreads();
    if (t < 64) {
        float v = red[t];
        v += __shfl_xor(v, 1);  v += __shfl_xor(v, 2);  v += __shfl_xor(v, 4);
        v += __shfl_xor(v, 8);  v += __shfl_xor(v, 16); v += __shfl_xor(v, 32);
        if (t == 0) out[blockIdx.x] = v + bias[o];
    }
}

extern "C" void kernel_launch(void* const* d_in, const int* in_sizes, int n_in,
                              void* d_out, int out_size, void* d_ws, size_t ws_size,
                              hipStream_t stream) {
    (void)in_sizes; (void)n_in; (void)out_size; (void)ws_size;
    const float* x    = (const float*)d_in[0];
    const float* w1   = (const float*)d_in[1];
    const float* b1   = (const float*)d_in[2];
    const float* w2   = (const float*)d_in[3];
    const float* b2   = (const float*)d_in[4];
    const float* w3   = (const float*)d_in[5];
    const float* b3   = (const float*)d_in[6];
    const float* bias = (const float*)d_in[7];
    float* out = (float*)d_out;

    unsigned short* h2T = (unsigned short*)d_ws;                       // 2.10 MB
    const size_t H2T_BYTES = (size_t)(LPOS / 64) * CUNITS * 16;
    unsigned short* gp = (unsigned short*)((char*)d_ws + H2T_BYTES);   // 34.6 MB
    const size_t GP_BYTES = (size_t)KSPLIT * GELEMS * 2;
    float* g = (float*)((char*)d_ws + H2T_BYTES + GP_BYTES);           // 2.16 MB

    k1_siren<<<LPOS / 16, 256, 0, stream>>>(w1, b1, w2, b2, h2T);
    k2_gemm<<<dim3(M_TOT / 128, KSPLIT), 256, 0, stream>>>(x, h2T, gp);
    reduce_g<<<GELEMS / 4 / 256, 256, 0, stream>>>(gp, g);
    k3_contract<<<64 * 64, 256, 0, stream>>>(g, w3, b3, bias, out);
}